// Round 12
// baseline (80.566 us; speedup 1.0000x reference)
//
#include <hip/hip_runtime.h>
#include <math.h>

#define D 64
#define EPS 1e-6f
#define SLOPE 0.2f

typedef _Float16 f16;
typedef _Float16 f16x4 __attribute__((ext_vector_type(4)));
typedef _Float16 f16x8 __attribute__((ext_vector_type(8)));
typedef float f32x4 __attribute__((ext_vector_type(4)));

__device__ __forceinline__ float red4(float v) {
  v += __shfl_xor(v, 16, 64);
  v += __shfl_xor(v, 32, 64);
  return v;
}
__device__ __forceinline__ float leaky(float l) {
  return (l > 0.f) ? l : SLOPE * l;
}

// ---------------------------------------------------------------------------
// W prep -> FRAGMENT-MAJOR f16 layout (see R5 notes).
// ---------------------------------------------------------------------------
__global__ void wprep_kernel(const float* __restrict__ Ww,
                             const float* __restrict__ W1w,
                             const float* __restrict__ W2w,
                             f16* __restrict__ wt)
{
  int i = blockIdx.x * blockDim.x + threadIdx.x;
  if (i >= 3 * 4096) return;
  int mat = i >> 12, idx = i & 4095;
  int n = idx >> 6, k = idx & 63;
  const float* src = (mat == 0) ? Ww : (mat == 1) ? W1w : W2w;
  int t = n >> 4, mloc = n & 15;
  int c = k >> 4, grp = (k >> 2) & 3, j = k & 3;
  int frag = mat * 16 + t * 4 + c;
  int lane = grp * 16 + mloc;
  wt[(frag << 8) + (lane << 2) + j] = (f16)src[k * 64 + n];
}

// ---------------------------------------------------------------------------
// Node kernel (R8 store layout — R10's "contiguous" f16x4 store was actually
// a 64-line scatter per instruction and regressed; the scalar store is 4x32B
// segments per instruction).  Weights in VGPRs, grid-stride, 2-deep prefetch.
// ---------------------------------------------------------------------------
__global__ __launch_bounds__(256, 2) void node_kernel(
    const float* __restrict__ query, const float* __restrict__ input_,
    const f16* __restrict__ wt,
    const float* __restrict__ Wb,  const float* __restrict__ W1b,
    const float* __restrict__ W2b,
    const float* __restrict__ g1,  const float* __restrict__ b1,
    f16* __restrict__ dense_h, float* __restrict__ s1, float* __restrict__ s2,
    int N)
{
  const int lane = threadIdx.x & 63;
  const int grp  = lane >> 4;
  const int mloc = lane & 15;
  const int wave  = blockIdx.x * (blockDim.x >> 6) + (threadIdx.x >> 6);
  const int nwav  = gridDim.x * (blockDim.x >> 6);
  const int TILES = (N + 15) >> 4;

  f16x4 wd[4][4], w1r[4][4], w2r[4][4];
#pragma unroll
  for (int t = 0; t < 4; ++t)
#pragma unroll
    for (int c = 0; c < 4; ++c) {
      int f = t * 4 + c;
      wd[t][c]  = *(const f16x4*)(wt + ((f)      << 8) + (lane << 2));
      w1r[t][c] = *(const f16x4*)(wt + ((16 + f) << 8) + (lane << 2));
      w2r[t][c] = *(const f16x4*)(wt + ((32 + f) << 8) + (lane << 2));
    }
  f32x4 gk[4], bk[4];
#pragma unroll
  for (int c = 0; c < 4; ++c) {
    gk[c] = *(const f32x4*)(g1 + c * 16 + grp * 4);
    bk[c] = *(const f32x4*)(b1 + c * 16 + grp * 4);
  }
  float wbr[4];
#pragma unroll
  for (int t = 0; t < 4; ++t) wbr[t] = Wb[t * 16 + mloc];

  auto prefetch = [&](f32x4* QB, f32x4* IB, int tl) {
    int m = tl * 16 + mloc;
    bool v = (tl < TILES) && (m < N);
    size_t b = (size_t)m * D;
#pragma unroll
    for (int c = 0; c < 4; ++c) {
      int k0 = c * 16 + grp * 4;
      if (v) {
        QB[c] = *(const f32x4*)(query + b + k0);
        IB[c] = *(const f32x4*)(input_ + b + k0);
      } else {
        QB[c] = (f32x4){0.f, 0.f, 0.f, 0.f};
        IB[c] = (f32x4){0.f, 0.f, 0.f, 0.f};
      }
    }
  };

  auto process = [&](f32x4* QB, f32x4* IB, int tl) {
    float s = 0.f;
#pragma unroll
    for (int c = 0; c < 4; ++c)
#pragma unroll
      for (int j = 0; j < 4; ++j) s += IB[c][j];
    s = red4(s);
    float mu = s * (1.f / D);
    float v2 = 0.f;
#pragma unroll
    for (int c = 0; c < 4; ++c)
#pragma unroll
      for (int j = 0; j < 4; ++j) {
        float d = IB[c][j] - mu;
        v2 += d * d;
      }
    v2 = red4(v2);
    float rs = rsqrtf(v2 * (1.f / D) + EPS);

    f16x4 xh[4], qh[4];
#pragma unroll
    for (int c = 0; c < 4; ++c)
#pragma unroll
      for (int j = 0; j < 4; ++j) {
        xh[c][j] = (f16)((IB[c][j] - mu) * rs * gk[c][j] + bk[c][j]);
        qh[c][j] = (f16)QB[c][j];
      }

    const int m  = tl * 16 + mloc;
    const bool mv = (m < N);

    // dense = X @ Ww + Wb -> f16 (scalar stores: 4x32B segments/instr)
#pragma unroll
    for (int t = 0; t < 4; ++t) {
      f32x4 acc = {0.f, 0.f, 0.f, 0.f};
#pragma unroll
      for (int c = 0; c < 4; ++c)
        acc = __builtin_amdgcn_mfma_f32_16x16x16f16(xh[c], wd[t][c], acc, 0, 0, 0);
#pragma unroll
      for (int r = 0; r < 4; ++r) {
        int row = tl * 16 + grp * 4 + r;
        if (row < N)
          dense_h[(size_t)row * D + t * 16 + mloc] = (f16)(acc[r] + wbr[t]);
      }
    }

    // scores: C-row index == fragment-k index -> lane-local dots
    float dot1 = 0.f, dot2 = 0.f;
#pragma unroll
    for (int t = 0; t < 4; ++t) {
      f32x4 a1 = {0.f, 0.f, 0.f, 0.f}, a2 = {0.f, 0.f, 0.f, 0.f};
#pragma unroll
      for (int c = 0; c < 4; ++c) {
        a1 = __builtin_amdgcn_mfma_f32_16x16x16f16(w1r[t][c], qh[c], a1, 0, 0, 0);
        a2 = __builtin_amdgcn_mfma_f32_16x16x16f16(w2r[t][c], xh[c], a2, 0, 0, 0);
      }
      f32x4 b1v = *(const f32x4*)(W1b + t * 16 + grp * 4);
      f32x4 b2v = *(const f32x4*)(W2b + t * 16 + grp * 4);
#pragma unroll
      for (int r = 0; r < 4; ++r) {
        dot1 += (a1[r] + b1v[r]) * (float)qh[t][r];
        dot2 += (a2[r] + b2v[r]) * (float)xh[t][r];
      }
    }
    dot1 = red4(dot1);
    dot2 = red4(dot2);
    if (grp == 0 && mv) {
      s1[m] = tanhf(dot1);
      s2[m] = tanhf(dot2);
    }
  };

  f32x4 qA[4], iA[4], qB[4], iB[4];
  int tl = wave;
  prefetch(qA, iA, tl);
  while (tl < TILES) {
    prefetch(qB, iB, tl + nwav);
    process(qA, iA, tl);
    tl += nwav;
    if (tl >= TILES) break;
    prefetch(qA, iA, tl + nwav);
    process(qB, iB, tl);
    tl += nwav;
  }
}

// ---------------------------------------------------------------------------
// CSR row pointers from the sorted edge_row array.
// ---------------------------------------------------------------------------
__global__ void rowptr_kernel(const int* __restrict__ erow,
                              int* __restrict__ row_ptr, int E, int N)
{
  int e = blockIdx.x * blockDim.x + threadIdx.x;
  if (e >= E) return;
  int r = erow[e];
  if (e == 0) {
    for (int rr = 0; rr <= r; ++rr) row_ptr[rr] = 0;
  } else {
    int rp = erow[e - 1];
    for (int rr = rp + 1; rr <= r; ++rr) row_ptr[rr] = e;
  }
  if (e == E - 1) {
    for (int rr = r + 1; rr <= N; ++rr) row_ptr[rr] = E;
  }
}

// ---------------------------------------------------------------------------
// accum<NIT>: per-iteration DIRECT edge fetch — no ds_bpermute, no prologue.
// Lane = 8*eg + fl.  eg 0..3 serve the low half's row, 4..7 the high half's.
// Iteration it handles slot 4*it + (eg&3): the 8 lanes of the eg-group load
// the same ecol/s2 values (broadcast lines) and recompute exp redundantly
// (1 VALU instr/iter for the whole wave); then gather the edge's f16 dense
// row as f16x8 (16B/lane).  Every iteration is an independent 3-deep load
// chain -> pure ILP, VMEM queue fills, no serial dependency on a prologue.
// ---------------------------------------------------------------------------
template <int NIT>
__device__ __forceinline__ void accum(const f16* __restrict__ dense_h,
                                      const int* __restrict__ ecol,
                                      const float* __restrict__ s2v,
                                      int base, int dgx, float s1x,
                                      int eg, int fl, float* A)
{
#pragma unroll
  for (int it = 0; it < NIT; ++it) {
    int slot = (it << 2) + (eg & 3);
    if (slot < dgx) {
      int   c = ecol[base + slot];
      float w = __expf(leaky(s1x + s2v[c]));
      f16x8 v = *(const f16x8*)(dense_h + (size_t)c * D + (fl << 3));
#pragma unroll
      for (int j = 0; j < 8; ++j)
        A[j] = fmaf((float)v[j], w, A[j]);
    }
  }
}

// ---------------------------------------------------------------------------
// Edge kernel v7: 2 rows/wave (half-wave each), direct per-iteration edge
// fetch (no DS), template-unrolled for deg<=32, runtime loop beyond.
// No softmax denominator (LN2 absorbs positive row scaling).
// ---------------------------------------------------------------------------
__global__ __launch_bounds__(256) void edge_kernel(
    const int* __restrict__ row_ptr, const int* __restrict__ ecol,
    const float* __restrict__ s1v, const float* __restrict__ s2v,
    const f16* __restrict__ dense_h,
    const float* __restrict__ g2, const float* __restrict__ b2,
    float* __restrict__ out, int N)
{
  const int lane = threadIdx.x & 63;
  const int eg   = lane >> 3;          // 0..7 (edge sub-group)
  const int fl   = lane & 7;           // feature octet 0..7
  const int wv   = blockIdx.x * (blockDim.x >> 6) + (threadIdx.x >> 6);
  const int r0   = wv << 1;
  const int r1   = r0 + 1;
  if (r0 >= N) return;

  const int pa = row_ptr[r0];
  const int pb = row_ptr[r0 + 1];
  const int pc = row_ptr[min(r0 + 2, N)];
  const int d0 = pb - pa;
  const int d1 = (r1 < N) ? (pc - pb) : 0;

  const bool hi  = (eg >= 4);
  const int  dgx = hi ? d1 : d0;
  const int  bse = hi ? pb : pa;
  const float s1x = s1v[hi ? min(r1, N - 1) : r0];

  float A[8] = {0.f, 0.f, 0.f, 0.f, 0.f, 0.f, 0.f, 0.f};
  const int maxd = max(d0, d1);
  const int nit  = (maxd + 3) >> 2;

  if      (nit <= 2) accum<2>(dense_h, ecol, s2v, bse, dgx, s1x, eg, fl, A);
  else if (nit <= 4) accum<4>(dense_h, ecol, s2v, bse, dgx, s1x, eg, fl, A);
  else if (nit <= 6) accum<6>(dense_h, ecol, s2v, bse, dgx, s1x, eg, fl, A);
  else if (nit <= 8) accum<8>(dense_h, ecol, s2v, bse, dgx, s1x, eg, fl, A);
  else {
    // runtime loop for deg > 32 (rare); same independent-chain body
    for (int it = 0; it < nit; ++it) {
      int slot = (it << 2) + (eg & 3);
      if (slot < dgx) {
        int   c = ecol[bse + slot];
        float w = __expf(leaky(s1x + s2v[c]));
        f16x8 v = *(const f16x8*)(dense_h + (size_t)c * D + (fl << 3));
#pragma unroll
        for (int j = 0; j < 8; ++j)
          A[j] = fmaf((float)v[j], w, A[j]);
      }
    }
  }

  // ---- reduce over the 4 sub-groups within each half ----
#pragma unroll
  for (int j = 0; j < 8; ++j) {
    A[j] += __shfl_xor(A[j], 8, 64);
    A[j] += __shfl_xor(A[j], 16, 64);
  }

  // ---- LN2 stats per half (8-lane feature reduce) ----
  float sa = 0.f, sq = 0.f;
#pragma unroll
  for (int j = 0; j < 8; ++j) {
    sa += A[j];
    sq += A[j] * A[j];
  }
#pragma unroll
  for (int m = 4; m > 0; m >>= 1) {
    sa += __shfl_xor(sa, m, 64);
    sq += __shfl_xor(sq, m, 64);
  }
  float mu  = sa * (1.f / D);
  float var = fmaxf(sq * (1.f / D) - mu * mu, 0.f);
  float rs  = rsqrtf(var + EPS);

  f32x4 gv0 = *(const f32x4*)(g2 + (fl << 3));
  f32x4 gv1 = *(const f32x4*)(g2 + (fl << 3) + 4);
  f32x4 bv0 = *(const f32x4*)(b2 + (fl << 3));
  f32x4 bv1 = *(const f32x4*)(b2 + (fl << 3) + 4);

  f32x4 o0, o1;
#pragma unroll
  for (int j = 0; j < 4; ++j) {
    o0[j] = (A[j]     - mu) * rs * gv0[j] + bv0[j];
    o1[j] = (A[j + 4] - mu) * rs * gv1[j] + bv1[j];
  }
  if (eg == 0) {
    *(f32x4*)(out + (size_t)r0 * D + (fl << 3))     = o0;
    *(f32x4*)(out + (size_t)r0 * D + (fl << 3) + 4) = o1;
  } else if (eg == 4 && r1 < N) {
    *(f32x4*)(out + (size_t)r1 * D + (fl << 3))     = o0;
    *(f32x4*)(out + (size_t)r1 * D + (fl << 3) + 4) = o1;
  }
}

// ---------------------------------------------------------------------------
extern "C" void kernel_launch(void* const* d_in, const int* in_sizes, int n_in,
                              void* d_out, int out_size, void* d_ws, size_t ws_size,
                              hipStream_t stream)
{
  const float* query  = (const float*)d_in[0];
  const float* input_ = (const float*)d_in[1];
  const int*   erow   = (const int*)d_in[2];
  const int*   ecol   = (const int*)d_in[3];
  const float* Ww     = (const float*)d_in[4];
  const float* Wb     = (const float*)d_in[5];
  const float* W1w    = (const float*)d_in[6];
  const float* W1b    = (const float*)d_in[7];
  const float* W2w    = (const float*)d_in[8];
  const float* W2b    = (const float*)d_in[9];
  const float* g1     = (const float*)d_in[10];
  const float* b1     = (const float*)d_in[11];
  const float* g2     = (const float*)d_in[12];
  const float* b2     = (const float*)d_in[13];

  const int N = in_sizes[0] / D;
  const int E = in_sizes[2];
  float* out = (float*)d_out;

  // ws: dense_h f16[N*D] | s1[N] | s2[N] | row_ptr[N+1] | wt f16
  char* ws = (char*)d_ws;
  f16*   dense_h = (f16*)ws;
  float* s1      = (float*)(ws + (size_t)N * D * sizeof(f16));
  float* s2      = s1 + N;
  int*   row_ptr = (int*)(s2 + N);
  uintptr_t wtp  = (uintptr_t)(row_ptr + N + 1);
  wtp = (wtp + 15) & ~(uintptr_t)15;
  f16* wt = (f16*)wtp;

  wprep_kernel<<<(3 * 4096 + 255) / 256, 256, 0, stream>>>(Ww, W1w, W2w, wt);
  node_kernel<<<512, 256, 0, stream>>>(query, input_, wt, Wb, W1b,
                                       W2b, g1, b1, dense_h, s1, s2, N);
  rowptr_kernel<<<(E + 255) / 256, 256, 0, stream>>>(erow, row_ptr, E, N);
  const int waves = (N + 1) / 2;
  edge_kernel<<<(waves + 3) / 4, 256, 0, stream>>>(row_ptr, ecol, s1, s2,
                                                   dense_h, g2, b2, out, N);
}

// Round 13
// 73.958 us; speedup vs baseline: 1.0894x; 1.0894x over previous
//
#include <hip/hip_runtime.h>
#include <math.h>

#define D 64
#define EPS 1e-6f
#define SLOPE 0.2f

typedef _Float16 f16;
typedef _Float16 f16x4 __attribute__((ext_vector_type(4)));
typedef _Float16 f16x8 __attribute__((ext_vector_type(8)));
typedef float f32x4 __attribute__((ext_vector_type(4)));

__device__ __forceinline__ float red4(float v) {
  v += __shfl_xor(v, 16, 64);
  v += __shfl_xor(v, 32, 64);
  return v;
}
__device__ __forceinline__ float leaky(float l) {
  return (l > 0.f) ? l : SLOPE * l;
}
__device__ __forceinline__ float bperm_f(int byte_addr, float v) {
  return __int_as_float(
      __builtin_amdgcn_ds_bpermute(byte_addr, __float_as_int(v)));
}
__device__ __forceinline__ int bperm_i(int byte_addr, int v) {
  return __builtin_amdgcn_ds_bpermute(byte_addr, v);
}

// ---------------------------------------------------------------------------
// W prep -> FRAGMENT-MAJOR f16 layout (see R5 notes).
// ---------------------------------------------------------------------------
__global__ void wprep_kernel(const float* __restrict__ Ww,
                             const float* __restrict__ W1w,
                             const float* __restrict__ W2w,
                             f16* __restrict__ wt)
{
  int i = blockIdx.x * blockDim.x + threadIdx.x;
  if (i >= 3 * 4096) return;
  int mat = i >> 12, idx = i & 4095;
  int n = idx >> 6, k = idx & 63;
  const float* src = (mat == 0) ? Ww : (mat == 1) ? W1w : W2w;
  int t = n >> 4, mloc = n & 15;
  int c = k >> 4, grp = (k >> 2) & 3, j = k & 3;
  int frag = mat * 16 + t * 4 + c;
  int lane = grp * 16 + mloc;
  wt[(frag << 8) + (lane << 2) + j] = (f16)src[k * 64 + n];
}

// ---------------------------------------------------------------------------
// Node kernel (R9-measured config: R8 scalar store, 512 blocks = 2 resident
// blocks/CU single round).  Weights in VGPRs, grid-stride, 2-deep prefetch.
// ---------------------------------------------------------------------------
__global__ __launch_bounds__(256, 2) void node_kernel(
    const float* __restrict__ query, const float* __restrict__ input_,
    const f16* __restrict__ wt,
    const float* __restrict__ Wb,  const float* __restrict__ W1b,
    const float* __restrict__ W2b,
    const float* __restrict__ g1,  const float* __restrict__ b1,
    f16* __restrict__ dense_h, float* __restrict__ s1, float* __restrict__ s2,
    int N)
{
  const int lane = threadIdx.x & 63;
  const int grp  = lane >> 4;
  const int mloc = lane & 15;
  const int wave  = blockIdx.x * (blockDim.x >> 6) + (threadIdx.x >> 6);
  const int nwav  = gridDim.x * (blockDim.x >> 6);
  const int TILES = (N + 15) >> 4;

  f16x4 wd[4][4], w1r[4][4], w2r[4][4];
#pragma unroll
  for (int t = 0; t < 4; ++t)
#pragma unroll
    for (int c = 0; c < 4; ++c) {
      int f = t * 4 + c;
      wd[t][c]  = *(const f16x4*)(wt + ((f)      << 8) + (lane << 2));
      w1r[t][c] = *(const f16x4*)(wt + ((16 + f) << 8) + (lane << 2));
      w2r[t][c] = *(const f16x4*)(wt + ((32 + f) << 8) + (lane << 2));
    }
  f32x4 gk[4], bk[4];
#pragma unroll
  for (int c = 0; c < 4; ++c) {
    gk[c] = *(const f32x4*)(g1 + c * 16 + grp * 4);
    bk[c] = *(const f32x4*)(b1 + c * 16 + grp * 4);
  }
  float wbr[4];
#pragma unroll
  for (int t = 0; t < 4; ++t) wbr[t] = Wb[t * 16 + mloc];

  auto prefetch = [&](f32x4* QB, f32x4* IB, int tl) {
    int m = tl * 16 + mloc;
    bool v = (tl < TILES) && (m < N);
    size_t b = (size_t)m * D;
#pragma unroll
    for (int c = 0; c < 4; ++c) {
      int k0 = c * 16 + grp * 4;
      if (v) {
        QB[c] = *(const f32x4*)(query + b + k0);
        IB[c] = *(const f32x4*)(input_ + b + k0);
      } else {
        QB[c] = (f32x4){0.f, 0.f, 0.f, 0.f};
        IB[c] = (f32x4){0.f, 0.f, 0.f, 0.f};
      }
    }
  };

  auto process = [&](f32x4* QB, f32x4* IB, int tl) {
    float s = 0.f;
#pragma unroll
    for (int c = 0; c < 4; ++c)
#pragma unroll
      for (int j = 0; j < 4; ++j) s += IB[c][j];
    s = red4(s);
    float mu = s * (1.f / D);
    float v2 = 0.f;
#pragma unroll
    for (int c = 0; c < 4; ++c)
#pragma unroll
      for (int j = 0; j < 4; ++j) {
        float d = IB[c][j] - mu;
        v2 += d * d;
      }
    v2 = red4(v2);
    float rs = rsqrtf(v2 * (1.f / D) + EPS);

    f16x4 xh[4], qh[4];
#pragma unroll
    for (int c = 0; c < 4; ++c)
#pragma unroll
      for (int j = 0; j < 4; ++j) {
        xh[c][j] = (f16)((IB[c][j] - mu) * rs * gk[c][j] + bk[c][j]);
        qh[c][j] = (f16)QB[c][j];
      }

    const int m  = tl * 16 + mloc;
    const bool mv = (m < N);

    // dense = X @ Ww + Wb -> f16 (scalar stores: 4x32B segments/instr)
#pragma unroll
    for (int t = 0; t < 4; ++t) {
      f32x4 acc = {0.f, 0.f, 0.f, 0.f};
#pragma unroll
      for (int c = 0; c < 4; ++c)
        acc = __builtin_amdgcn_mfma_f32_16x16x16f16(xh[c], wd[t][c], acc, 0, 0, 0);
#pragma unroll
      for (int r = 0; r < 4; ++r) {
        int row = tl * 16 + grp * 4 + r;
        if (row < N)
          dense_h[(size_t)row * D + t * 16 + mloc] = (f16)(acc[r] + wbr[t]);
      }
    }

    // scores: C-row index == fragment-k index -> lane-local dots
    float dot1 = 0.f, dot2 = 0.f;
#pragma unroll
    for (int t = 0; t < 4; ++t) {
      f32x4 a1 = {0.f, 0.f, 0.f, 0.f}, a2 = {0.f, 0.f, 0.f, 0.f};
#pragma unroll
      for (int c = 0; c < 4; ++c) {
        a1 = __builtin_amdgcn_mfma_f32_16x16x16f16(w1r[t][c], qh[c], a1, 0, 0, 0);
        a2 = __builtin_amdgcn_mfma_f32_16x16x16f16(w2r[t][c], xh[c], a2, 0, 0, 0);
      }
      f32x4 b1v = *(const f32x4*)(W1b + t * 16 + grp * 4);
      f32x4 b2v = *(const f32x4*)(W2b + t * 16 + grp * 4);
#pragma unroll
      for (int r = 0; r < 4; ++r) {
        dot1 += (a1[r] + b1v[r]) * (float)qh[t][r];
        dot2 += (a2[r] + b2v[r]) * (float)xh[t][r];
      }
    }
    dot1 = red4(dot1);
    dot2 = red4(dot2);
    if (grp == 0 && mv) {
      s1[m] = tanhf(dot1);
      s2[m] = tanhf(dot2);
    }
  };

  f32x4 qA[4], iA[4], qB[4], iB[4];
  int tl = wave;
  prefetch(qA, iA, tl);
  while (tl < TILES) {
    prefetch(qB, iB, tl + nwav);
    process(qA, iA, tl);
    tl += nwav;
    if (tl >= TILES) break;
    prefetch(qA, iA, tl + nwav);
    process(qB, iB, tl);
    tl += nwav;
  }
}

// ---------------------------------------------------------------------------
// CSR row pointers from the sorted edge_row array.
// ---------------------------------------------------------------------------
__global__ void rowptr_kernel(const int* __restrict__ erow,
                              int* __restrict__ row_ptr, int E, int N)
{
  int e = blockIdx.x * blockDim.x + threadIdx.x;
  if (e >= E) return;
  int r = erow[e];
  if (e == 0) {
    for (int rr = 0; rr <= r; ++rr) row_ptr[rr] = 0;
  } else {
    int rp = erow[e - 1];
    for (int rr = rp + 1; rr <= r; ++rr) row_ptr[rr] = e;
  }
  if (e == E - 1) {
    for (int rr = r + 1; rr <= N; ++rr) row_ptr[rr] = E;
  }
}

// ---------------------------------------------------------------------------
// accum<NIT>: fully-unrolled bpermute gather/accumulate engine (R8/R10).
// ---------------------------------------------------------------------------
template <int NIT>
__device__ __forceinline__ void accum(const f16* __restrict__ dense_h,
                                      int eg, int fl, int c, float w,
                                      float* A)
{
#pragma unroll
  for (int it = 0; it < NIT; ++it) {
    int a = (((eg & 4) << 3) + (it << 2) + (eg & 3)) << 2;
    float wb = bperm_f(a, w);
    int   cb = bperm_i(a, c);
    f16x8 v = *(const f16x8*)(dense_h + (size_t)cb * D + (fl << 3));
#pragma unroll
    for (int j = 0; j < 8; ++j)
      A[j] = fmaf((float)v[j], wb, A[j]);
  }
}

// ---------------------------------------------------------------------------
// Edge kernel v6 (R10-measured 43.0us): grid-stride pair loop, 2-deep
// pipelined prologue, 2 rows/wave half-wave slot ownership, no softmax
// denominator (LN2 absorbs positive row scaling).
// ---------------------------------------------------------------------------
__global__ __launch_bounds__(256) void edge_kernel(
    const int* __restrict__ row_ptr, const int* __restrict__ ecol,
    const float* __restrict__ s1v, const float* __restrict__ s2v,
    const f16* __restrict__ dense_h,
    const float* __restrict__ g2, const float* __restrict__ b2,
    float* __restrict__ out, int N, int npairs)
{
  const int lane = threadIdx.x & 63;
  const int eg   = lane >> 3;          // 0..7 (edge sub-group)
  const int fl   = lane & 7;           // feature octet 0..7
  const bool hi  = (lane >= 32);
  const int  sl  = lane & 31;          // slot within the half's row
  const int wv0  = blockIdx.x * (blockDim.x >> 6) + (threadIdx.x >> 6);
  const int nwav = gridDim.x * (blockDim.x >> 6);

  const f32x4 gv0 = *(const f32x4*)(g2 + (fl << 3));
  const f32x4 gv1 = *(const f32x4*)(g2 + (fl << 3) + 4);
  const f32x4 bv0 = *(const f32x4*)(b2 + (fl << 3));
  const f32x4 bv1 = *(const f32x4*)(b2 + (fl << 3) + 4);

  auto prologue = [&](int pv, int& c, float& w, int& d0, int& d1,
                      int& pa, int& pb, int& pc) {
    c = 0; w = 0.f; d0 = 0; d1 = 0; pa = 0; pb = 0; pc = 0;
    if (pv >= npairs) return;
    int r0 = pv << 1;
    pa = row_ptr[r0];
    pb = row_ptr[r0 + 1];
    pc = row_ptr[min(r0 + 2, N)];
    d0 = pb - pa;
    d1 = (r0 + 1 < N) ? (pc - pb) : 0;
    int dgx = hi ? d1 : d0;
    int bse = hi ? pb : pa;
    float s1x = s1v[min(r0 + (hi ? 1 : 0), N - 1)];
    if (sl < dgx) {
      c = ecol[bse + sl];
      w = __expf(leaky(s1x + s2v[c]));
    }
  };

  auto process = [&](int pv, int c, float w, int d0, int d1,
                     int pa, int pb, int pc) {
    if (pv >= npairs) return;
    const int r0 = pv << 1;
    const int r1 = r0 + 1;
    float A[8] = {0.f, 0.f, 0.f, 0.f, 0.f, 0.f, 0.f, 0.f};
    const int maxd = max(d0, d1);

    if (maxd <= 32) {
      const int nit = (maxd + 3) >> 2;
      if      (nit <= 2) accum<2>(dense_h, eg, fl, c, w, A);
      else if (nit <= 4) accum<4>(dense_h, eg, fl, c, w, A);
      else if (nit <= 6) accum<6>(dense_h, eg, fl, c, w, A);
      else               accum<8>(dense_h, eg, fl, c, w, A);
    } else {
      // rare generic path (deg > 32): full wave per row, 64-slot blocks
      float A0[8] = {0.f, 0.f, 0.f, 0.f, 0.f, 0.f, 0.f, 0.f};
      float A1[8] = {0.f, 0.f, 0.f, 0.f, 0.f, 0.f, 0.f, 0.f};
      auto rowacc = [&](int st, int en, float s1i, float* Ar) {
        for (int b = st; b < en; b += 64) {
          int nb = min(64, en - b);
          int cc = 0;
          float ww = 0.f;
          if (lane < nb) {
            cc = ecol[b + lane];
            ww = __expf(leaky(s1i + s2v[cc]));
          }
#pragma unroll
          for (int it = 0; it < 8; ++it) {
            int a = ((it << 3) + eg) << 2;
            float wb = bperm_f(a, ww);
            int   cb = bperm_i(a, cc);
            f16x8 v = *(const f16x8*)(dense_h + (size_t)cb * D + (fl << 3));
#pragma unroll
            for (int j = 0; j < 8; ++j)
              Ar[j] = fmaf((float)v[j], wb, Ar[j]);
          }
        }
      };
      rowacc(pa, pb, s1v[r0], A0);
      if (r1 < N) rowacc(pb, pc, s1v[r1], A1);
#pragma unroll
      for (int j = 0; j < 8; ++j) {
        A0[j] += __shfl_xor(A0[j], 32, 64);
        A1[j] += __shfl_xor(A1[j], 32, 64);
        A[j] = hi ? A1[j] : A0[j];
      }
    }

#pragma unroll
    for (int j = 0; j < 8; ++j) {
      A[j] += __shfl_xor(A[j], 8, 64);
      A[j] += __shfl_xor(A[j], 16, 64);
    }

    float sa = 0.f, sq = 0.f;
#pragma unroll
    for (int j = 0; j < 8; ++j) {
      sa += A[j];
      sq += A[j] * A[j];
    }
#pragma unroll
    for (int m = 4; m > 0; m >>= 1) {
      sa += __shfl_xor(sa, m, 64);
      sq += __shfl_xor(sq, m, 64);
    }
    float mu  = sa * (1.f / D);
    float var = fmaxf(sq * (1.f / D) - mu * mu, 0.f);
    float rs  = rsqrtf(var + EPS);

    f32x4 o0, o1;
#pragma unroll
    for (int j = 0; j < 4; ++j) {
      o0[j] = (A[j]     - mu) * rs * gv0[j] + bv0[j];
      o1[j] = (A[j + 4] - mu) * rs * gv1[j] + bv1[j];
    }
    if (eg == 0) {
      *(f32x4*)(out + (size_t)r0 * D + (fl << 3))     = o0;
      *(f32x4*)(out + (size_t)r0 * D + (fl << 3) + 4) = o1;
    } else if (eg == 4 && r1 < N) {
      *(f32x4*)(out + (size_t)r1 * D + (fl << 3))     = o0;
      *(f32x4*)(out + (size_t)r1 * D + (fl << 3) + 4) = o1;
    }
  };

  // ---- 2-deep pipelined pair loop (ping-pong state) ----
  int cA, d0A, d1A, paA, pbA, pcA;
  int cB, d0B, d1B, paB, pbB, pcB;
  float wA, wB;

  int pv = wv0;
  prologue(pv, cA, wA, d0A, d1A, paA, pbA, pcA);
  while (pv < npairs) {
    prologue(pv + nwav, cB, wB, d0B, d1B, paB, pbB, pcB);
    process(pv, cA, wA, d0A, d1A, paA, pbA, pcA);
    pv += nwav;
    if (pv >= npairs) break;
    prologue(pv + nwav, cA, wA, d0A, d1A, paA, pbA, pcA);
    process(pv, cB, wB, d0B, d1B, paB, pbB, pcB);
    pv += nwav;
  }
}

// ---------------------------------------------------------------------------
extern "C" void kernel_launch(void* const* d_in, const int* in_sizes, int n_in,
                              void* d_out, int out_size, void* d_ws, size_t ws_size,
                              hipStream_t stream)
{
  const float* query  = (const float*)d_in[0];
  const float* input_ = (const float*)d_in[1];
  const int*   erow   = (const int*)d_in[2];
  const int*   ecol   = (const int*)d_in[3];
  const float* Ww     = (const float*)d_in[4];
  const float* Wb     = (const float*)d_in[5];
  const float* W1w    = (const float*)d_in[6];
  const float* W1b    = (const float*)d_in[7];
  const float* W2w    = (const float*)d_in[8];
  const float* W2b    = (const float*)d_in[9];
  const float* g1     = (const float*)d_in[10];
  const float* b1     = (const float*)d_in[11];
  const float* g2     = (const float*)d_in[12];
  const float* b2     = (const float*)d_in[13];

  const int N = in_sizes[0] / D;
  const int E = in_sizes[2];
  float* out = (float*)d_out;

  // ws: dense_h f16[N*D] | s1[N] | s2[N] | row_ptr[N+1] | wt f16
  char* ws = (char*)d_ws;
  f16*   dense_h = (f16*)ws;
  float* s1      = (float*)(ws + (size_t)N * D * sizeof(f16));
  float* s2      = s1 + N;
  int*   row_ptr = (int*)(s2 + N);
  uintptr_t wtp  = (uintptr_t)(row_ptr + N + 1);
  wtp = (wtp + 15) & ~(uintptr_t)15;
  f16* wt = (f16*)wtp;

  wprep_kernel<<<(3 * 4096 + 255) / 256, 256, 0, stream>>>(Ww, W1w, W2w, wt);
  node_kernel<<<512, 256, 0, stream>>>(query, input_, wt, Wb, W1b,
                                       W2b, g1, b1, dense_h, s1, s2, N);
  rowptr_kernel<<<(E + 255) / 256, 256, 0, stream>>>(erow, row_ptr, E, N);
  const int npairs = (N + 1) / 2;
  edge_kernel<<<2048, 256, 0, stream>>>(row_ptr, ecol, s1, s2,
                                        dense_h, g2, b2, out, N, npairs);
}